// Round 3
// baseline (54.327 us; speedup 1.0000x reference)
//
#include <hip/hip_runtime.h>

// Constrained sparsemax, wave-per-row.
// p = clip(z - tau, 0, u), tau s.t. f(tau) = sum clip(z - tau, 0, u) = 1.
// Phase 1: Illinois false-position on g(tau) = sum med3(z-tau,0,u) - 1 in f32.
//          (one v_sub + v_med3 + v_add per element, ONE reduced value/iter)
// Phase 2: safeguarded f64 Newton on global bracket -> exact f64 root.
// One wave (64 lanes) per row, K=1024 -> 16 elems/lane in registers.
// All reductions are __shfl_xor butterflies (bit-identical on all lanes ->
// uniform branches, no LDS, no __syncthreads).

__global__ __launch_bounds__(256)
void csparsemax_kernel(const float* __restrict__ z, const float* __restrict__ u,
                       float* __restrict__ out, int B) {
  constexpr int K = 1024;
  const int lane = threadIdx.x & 63;
  const int wv = threadIdx.x >> 6;
  const int row = blockIdx.x * 4 + wv;
  if (row >= B) return;
  const size_t base = (size_t)row * (size_t)K;

  // --- load 16 elems/lane as 4x float4, coalesced ---
  float zf[16], uf[16];
  const float4* z4p = (const float4*)(z + base);
  const float4* u4p = (const float4*)(u + base);
  #pragma unroll
  for (int j = 0; j < 4; ++j) {
    float4 a = z4p[j * 64 + lane];
    float4 b = u4p[j * 64 + lane];
    zf[j*4+0] = a.x; zf[j*4+1] = a.y; zf[j*4+2] = a.z; zf[j*4+3] = a.w;
    uf[j*4+0] = b.x; uf[j*4+1] = b.y; uf[j*4+2] = b.z; uf[j*4+3] = b.w;
  }

  // --- bracket + sum(u): f(lo)=sum u (>=10 by construction), f(hi)=0 ---
  float lo = 3.4e38f, hi = -3.4e38f, su = 0.f;
  #pragma unroll
  for (int t = 0; t < 16; ++t) {
    lo = fminf(lo, zf[t] - uf[t]);
    hi = fmaxf(hi, zf[t]);
    su += uf[t];
  }
  #pragma unroll
  for (int m = 32; m; m >>= 1) {
    lo = fminf(lo, __shfl_xor(lo, m));
    hi = fmaxf(hi, __shfl_xor(hi, m));
    su += __shfl_xor(su, m);
  }
  const double glo = (double)lo, ghi = (double)hi;

  // --- phase 1: Illinois false-position on g(tau) = f(tau) - 1 ---
  float gl = su - 1.f;          // g(lo) > 0
  float gh = -1.f;              // g(hi) = -1
  float tau = (lo * gh - hi * gl) / (gh - gl);
  if (!(tau > lo && tau < hi)) tau = 0.5f * (lo + hi);
  int side = 0;
  for (int it = 0; it < 24; ++it) {
    float f0 = 0.f, f1 = 0.f, f2 = 0.f, f3 = 0.f;
    #pragma unroll
    for (int t = 0; t < 16; t += 4) {      // clamp = v_med3_f32
      f0 += fminf(fmaxf(zf[t+0] - tau, 0.f), uf[t+0]);
      f1 += fminf(fmaxf(zf[t+1] - tau, 0.f), uf[t+1]);
      f2 += fminf(fmaxf(zf[t+2] - tau, 0.f), uf[t+2]);
      f3 += fminf(fmaxf(zf[t+3] - tau, 0.f), uf[t+3]);
    }
    float g = (f0 + f1) + (f2 + f3);
    #pragma unroll
    for (int m = 32; m; m >>= 1) g += __shfl_xor(g, m);
    g -= 1.f;
    if (g > 0.f) {
      lo = tau; gl = g;
      if (side == 1) gh *= 0.5f;           // Illinois anti-stall
      side = 1;
    } else if (g < 0.f) {
      hi = tau; gh = g;
      if (side == -1) gl *= 0.5f;
      side = -1;
    } else break;                          // exact f32 root
    float next = (lo * gh - hi * gl) / (gh - gl);
    if (!(next > lo && next < hi)) next = 0.5f * (lo + hi);
    if (next == tau) break;                // f32 resolution reached
    tau = next;
  }

  // --- phase 2: safeguarded f64 Newton, global bracket (exactness) ---
  double dlo = glo, dhi = ghi;
  double taud = (double)tau;
  for (int it = 0; it < 30; ++it) {
    double S = 0.0;
    float Cf = 0.f;                        // count fits exactly in f32
    #pragma unroll
    for (int t = 0; t < 16; ++t) {
      double x = (double)zf[t] - taud;
      double ud = (double)uf[t];
      if (x >= ud)      { S += ud; }
      else if (x > 0.0) { S += (double)zf[t]; Cf += 1.f; }
    }
    #pragma unroll
    for (int m = 32; m; m >>= 1) {
      S += __shfl_xor(S, m);
      Cf += __shfl_xor(Cf, m);
    }
    double C = (double)Cf;
    double f = S - C * taud;
    if (f == 1.0 && C > 0.5) break;
    if (f > 1.0) dlo = taud; else dhi = taud;
    double next;
    if (C > 0.5) {
      double cand = (S - 1.0) / C;         // exact root of current segment
      if (cand == taud) break;
      next = (cand > dlo && cand < dhi) ? cand : 0.5 * (dlo + dhi);
    } else {
      next = 0.5 * (dlo + dhi);
    }
    if (next == taud) break;
    taud = next;
  }

  // --- epilogue: p, regions(as f32), tau, val (f64 compares = numpy's) ---
  float* out_p = out;
  float* out_r = out + (size_t)B * (size_t)K;
  float* out_t = out + 2ull * (size_t)B * (size_t)K;
  float* out_v = out_t + B;

  double vloc = 0.0;
  #pragma unroll
  for (int j = 0; j < 4; ++j) {
    float4 p4, r4;
    float pv[4], rv[4];
    #pragma unroll
    for (int q = 0; q < 4; ++q) {
      int t = j * 4 + q;
      double x = (double)zf[t] - taud;
      double ud = (double)uf[t];
      double p = x < 0.0 ? 0.0 : (x > ud ? ud : x);
      int reg = (p <= 0.0) ? 0 : ((p >= ud) ? 2 : 1);
      double d = p - (double)zf[t];
      vloc += d * d;
      pv[q] = (float)p;
      rv[q] = (float)reg;
    }
    p4.x = pv[0]; p4.y = pv[1]; p4.z = pv[2]; p4.w = pv[3];
    r4.x = rv[0]; r4.y = rv[1]; r4.z = rv[2]; r4.w = rv[3];
    ((float4*)(out_p + base))[j * 64 + lane] = p4;
    ((float4*)(out_r + base))[j * 64 + lane] = r4;
  }

  #pragma unroll
  for (int m = 32; m; m >>= 1) vloc += __shfl_xor(vloc, m);
  if (lane == 0) {
    out_t[row] = (float)taud;
    out_v[row] = (float)(0.5 * vloc);
  }
}

extern "C" void kernel_launch(void* const* d_in, const int* in_sizes, int n_in,
                              void* d_out, int out_size, void* d_ws, size_t ws_size,
                              hipStream_t stream) {
  const float* z = (const float*)d_in[0];
  const float* u = (const float*)d_in[1];
  float* out = (float*)d_out;
  const int K = 1024;
  const int B = in_sizes[0] / K;
  const int blocks = (B + 3) / 4;
  csparsemax_kernel<<<blocks, 256, 0, stream>>>(z, u, out, B);
}